// Round 1
// baseline (210.841 us; speedup 1.0000x reference)
//
#include <hip/hip_runtime.h>

// Problem constants (from reference setup_inputs)
#define BDIM 4096
#define DDIM 256
#define BM 64
#define BN 64
#define BK 32

// Number of upper-triangular pairs: B*(B-1)/2
#define NPAIRS 8386560.0

// Kernel 1: per-row squared norms; block 0 thread 0 also zeros the accumulator.
__global__ __launch_bounds__(256) void sqnorm_kernel(const float* __restrict__ E,
                                                     float* __restrict__ sq,
                                                     double* __restrict__ accum) {
    int row = blockIdx.x;
    int t = threadIdx.x;            // 256 threads, one per column
    float v = E[row * DDIM + t];
    float s = v * v;
    // wave-64 shuffle reduce
    #pragma unroll
    for (int off = 32; off > 0; off >>= 1) s += __shfl_down(s, off, 64);
    __shared__ float ws[4];
    int wave = t >> 6, lane = t & 63;
    if (lane == 0) ws[wave] = s;
    __syncthreads();
    if (t == 0) {
        sq[row] = ws[0] + ws[1] + ws[2] + ws[3];
        if (row == 0) *accum = 0.0;
    }
}

// Kernel 2: tiled gram + fused contrastive loss over upper-triangular pairs.
// Grid (64, 64); blocks with bj < bi exit immediately (triangular skip).
__global__ __launch_bounds__(256) void loss_kernel(const float* __restrict__ E,
                                                   const int* __restrict__ lab,
                                                   const float* __restrict__ sq,
                                                   double* __restrict__ accum) {
    int bi = blockIdx.y, bj = blockIdx.x;
    if (bj < bi) return;

    __shared__ float As[BM][BK + 1];   // +1 pad: kill 4-way bank conflict
    __shared__ float Bs[BN][BK + 1];

    int tid = threadIdx.x;
    int tx = tid & 15, ty = tid >> 4;  // 16x16 thread layout
    int m0 = ty * 4, n0 = tx * 4;      // 4x4 micro-tile per thread
    int i0 = bi * BM, j0 = bj * BN;

    float acc[4][4] = {};

    for (int k0 = 0; k0 < DDIM; k0 += BK) {
        // Cooperative load: 64x32 floats each, 8 per thread, coalesced per row
        for (int l = tid; l < BM * BK; l += 256) {
            int m = l >> 5, k = l & 31;
            As[m][k] = E[(i0 + m) * DDIM + k0 + k];
            Bs[m][k] = E[(j0 + m) * DDIM + k0 + k];
        }
        __syncthreads();
        #pragma unroll
        for (int k = 0; k < BK; k++) {
            float a[4], b[4];
            #pragma unroll
            for (int r = 0; r < 4; r++) a[r] = As[m0 + r][k];
            #pragma unroll
            for (int c = 0; c < 4; c++) b[c] = Bs[n0 + c][k];
            #pragma unroll
            for (int r = 0; r < 4; r++)
                #pragma unroll
                for (int c = 0; c < 4; c++)
                    acc[r][c] += a[r] * b[c];
        }
        __syncthreads();
    }

    // Fused loss over this tile's pairs (mask j > i)
    float lsum = 0.f;
    #pragma unroll
    for (int r = 0; r < 4; r++) {
        int gi = i0 + m0 + r;
        float sqi = sq[gi];
        int li = lab[gi];
        #pragma unroll
        for (int c = 0; c < 4; c++) {
            int gj = j0 + n0 + c;
            if (gj > gi) {
                float d2 = sqi + sq[gj] - 2.f * acc[r][c];
                d2 = fmaxf(d2, 0.f) + 1e-8f;          // matches ref: max(d2,0)+1e-8
                float loss;
                if (li == lab[gj]) {
                    loss = 0.5f * d2;                  // 0.5 * dist^2
                } else {
                    float dist = sqrtf(d2);
                    float mgn = fmaxf(1.0f - dist, 0.f);
                    loss = 0.5f * mgn * mgn;
                }
                lsum += loss;
            }
        }
    }

    // Block reduction: wave shuffle, then LDS across 4 waves, one atomic per block
    #pragma unroll
    for (int off = 32; off > 0; off >>= 1) lsum += __shfl_down(lsum, off, 64);
    __shared__ float wsum[4];
    int wave = tid >> 6, lane = tid & 63;
    if (lane == 0) wsum[wave] = lsum;
    __syncthreads();
    if (tid == 0) {
        double bs = (double)wsum[0] + (double)wsum[1] + (double)wsum[2] + (double)wsum[3];
        atomicAdd(accum, bs);
    }
}

// Kernel 3: final division, write scalar output
__global__ void finalize_kernel(const double* __restrict__ accum, float* __restrict__ out) {
    out[0] = (float)(*accum / (NPAIRS + 1e-8));
}

extern "C" void kernel_launch(void* const* d_in, const int* in_sizes, int n_in,
                              void* d_out, int out_size, void* d_ws, size_t ws_size,
                              hipStream_t stream) {
    const float* E = (const float*)d_in[0];
    const int* lab = (const int*)d_in[1];
    float* out = (float*)d_out;

    // Workspace layout: [0..7] double accumulator, [256..] sq norms (4096 floats)
    double* accum = (double*)d_ws;
    float* sq = (float*)((char*)d_ws + 256);

    sqnorm_kernel<<<BDIM, 256, 0, stream>>>(E, sq, accum);
    dim3 grid(BDIM / BN, BDIM / BM);
    loss_kernel<<<grid, 256, 0, stream>>>(E, lab, sq, accum);
    finalize_kernel<<<1, 1, 0, stream>>>(accum, out);
}

// Round 2
// 91.232 us; speedup vs baseline: 2.3111x; 2.3111x over previous
//
#include <hip/hip_runtime.h>

// Problem constants (from reference setup_inputs)
#define BDIM 4096
#define DDIM 256
#define NPAIRS 8386560.0   // B*(B-1)/2

typedef __attribute__((ext_vector_type(8))) short bf16x8;  // 8 bf16 = 4 VGPRs (MFMA A/B frag)
typedef __attribute__((ext_vector_type(4))) float f32x4;   // MFMA C/D frag

// ---------------------------------------------------------------------------
// Kernel 1: fp32 -> bf16 conversion (RTN) + per-row squared norms (fp32)
//           + zero the global double accumulator.
// Grid: 4096 blocks x 256 threads (one thread per element of a row).
// ---------------------------------------------------------------------------
__global__ __launch_bounds__(256) void prep_kernel(const float* __restrict__ E,
                                                   unsigned short* __restrict__ Ebf,
                                                   float* __restrict__ sq,
                                                   double* __restrict__ accum) {
    int row = blockIdx.x;
    int t = threadIdx.x;
    float v = E[row * DDIM + t];
    // round-to-nearest-even bf16
    unsigned int u = __builtin_bit_cast(unsigned int, v);
    unsigned int r = (u + 0x7fffu + ((u >> 16) & 1u)) >> 16;
    Ebf[row * DDIM + t] = (unsigned short)r;

    float s = v * v;
    #pragma unroll
    for (int off = 32; off > 0; off >>= 1) s += __shfl_down(s, off, 64);
    __shared__ float ws[4];
    int wave = t >> 6, lane = t & 63;
    if (lane == 0) ws[wave] = s;
    __syncthreads();
    if (t == 0) {
        sq[row] = ws[0] + ws[1] + ws[2] + ws[3];
        if (row == 0) *accum = 0.0;
    }
}

// ---------------------------------------------------------------------------
// Kernel 2: 128x128 gram tile via bf16 MFMA + fused contrastive loss.
// 256 threads = 4 waves in 2x2; each wave computes a 64x64 quadrant as a
// 4x4 grid of 16x16x32 MFMA fragments. K-loop over 256 in steps of 32 with
// global_load_lds width-16 staging (m97 structure). Triangular block skip.
// ---------------------------------------------------------------------------
__global__ __launch_bounds__(256) void loss_mfma_kernel(const unsigned short* __restrict__ Ebf,
                                                        const int* __restrict__ lab,
                                                        const float* __restrict__ sq,
                                                        double* __restrict__ accum) {
    int bi = blockIdx.y, bj = blockIdx.x;
    if (bj < bi) return;

    // LDS tiles: 128 rows x 32 k (bf16), row-major, NO padding
    // (global_load_lds requires dest = wave-uniform base + lane*16).
    __shared__ unsigned short As[128 * 32];   // 8 KB
    __shared__ unsigned short Bs[128 * 32];   // 8 KB

    int tid = threadIdx.x;
    int lane = tid & 63;
    int w = tid >> 6;
    int wr = w >> 1, wc = w & 1;              // wave's 64x64 quadrant
    int i0 = bi * 128, j0 = bj * 128;

    // Staging addresses: thread t covers LDS bytes t*16 (pass 1) / 4096+t*16 (pass 2).
    // LDS layout [m][k]: byte = m*64 + k*2  ->  m = t>>2, k = (t&3)*8.
    int sm = tid >> 2;                         // 0..63
    int sk = (tid & 3) * 8;                    // 0,8,16,24
    const unsigned short* gA = Ebf + (i0 + sm) * DDIM + sk;
    const unsigned short* gB = Ebf + (j0 + sm) * DDIM + sk;
    unsigned short* lA = As + tid * 8;         // byte offset tid*16
    unsigned short* lB = Bs + tid * 8;

    f32x4 acc[4][4] = {};

    int frow = lane & 15;                      // fragment row (A) / col-row (B^T)
    int q = lane >> 4;                         // quad: k-offset = q*8

    for (int k0 = 0; k0 < DDIM; k0 += 32) {
        __builtin_amdgcn_global_load_lds(
            (const __attribute__((address_space(1))) void*)(gA + k0),
            (__attribute__((address_space(3))) void*)lA, 16, 0, 0);
        __builtin_amdgcn_global_load_lds(
            (const __attribute__((address_space(1))) void*)(gA + 64 * DDIM + k0),
            (__attribute__((address_space(3))) void*)(lA + 2048), 16, 0, 0);
        __builtin_amdgcn_global_load_lds(
            (const __attribute__((address_space(1))) void*)(gB + k0),
            (__attribute__((address_space(3))) void*)lB, 16, 0, 0);
        __builtin_amdgcn_global_load_lds(
            (const __attribute__((address_space(1))) void*)(gB + 64 * DDIM + k0),
            (__attribute__((address_space(3))) void*)(lB + 2048), 16, 0, 0);
        __syncthreads();

        bf16x8 af[4], bfr[4];
        #pragma unroll
        for (int r = 0; r < 4; r++)
            af[r] = *(const bf16x8*)(As + (wr * 64 + r * 16 + frow) * 32 + q * 8);
        #pragma unroll
        for (int c = 0; c < 4; c++)
            bfr[c] = *(const bf16x8*)(Bs + (wc * 64 + c * 16 + frow) * 32 + q * 8);

        #pragma unroll
        for (int r = 0; r < 4; r++)
            #pragma unroll
            for (int c = 0; c < 4; c++)
                acc[r][c] = __builtin_amdgcn_mfma_f32_16x16x32_bf16(af[r], bfr[c], acc[r][c], 0, 0, 0);
        __syncthreads();
    }

    // Epilogue: C/D layout col = lane&15, row = (lane>>4)*4 + reg.
    int rowbase = i0 + wr * 64 + q * 4;
    int colbase = j0 + wc * 64 + frow;

    float sqi[16];
    int li[16];
    #pragma unroll
    for (int r = 0; r < 4; r++)
        #pragma unroll
        for (int reg = 0; reg < 4; reg++) {
            int gi = rowbase + r * 16 + reg;
            sqi[r * 4 + reg] = sq[gi];
            li[r * 4 + reg] = lab[gi];
        }

    float lsum = 0.f;
    #pragma unroll
    for (int c = 0; c < 4; c++) {
        int gj = colbase + c * 16;
        float sqj = sq[gj];
        int lj = lab[gj];
        #pragma unroll
        for (int r = 0; r < 4; r++) {
            #pragma unroll
            for (int reg = 0; reg < 4; reg++) {
                int gi = rowbase + r * 16 + reg;
                if (gj > gi) {
                    float d2 = sqi[r * 4 + reg] + sqj - 2.f * acc[r][c][reg];
                    d2 = fmaxf(d2, 0.f) + 1e-8f;
                    float loss;
                    if (li[r * 4 + reg] == lj) {
                        loss = 0.5f * d2;
                    } else {
                        float dist = sqrtf(d2);
                        float m1 = fmaxf(1.0f - dist, 0.f);
                        loss = 0.5f * m1 * m1;
                    }
                    lsum += loss;
                }
            }
        }
    }

    // Block reduction: wave shuffle -> LDS across 4 waves -> one atomic per block.
    #pragma unroll
    for (int off = 32; off > 0; off >>= 1) lsum += __shfl_down(lsum, off, 64);
    __shared__ float wsum[4];
    if (lane == 0) wsum[w] = lsum;
    __syncthreads();
    if (tid == 0) {
        double bs = (double)wsum[0] + (double)wsum[1] + (double)wsum[2] + (double)wsum[3];
        atomicAdd(accum, bs);
    }
}

// ---------------------------------------------------------------------------
// Kernel 3: final division, write scalar output
// ---------------------------------------------------------------------------
__global__ void finalize_kernel(const double* __restrict__ accum, float* __restrict__ out) {
    out[0] = (float)(*accum / (NPAIRS + 1e-8));
}

extern "C" void kernel_launch(void* const* d_in, const int* in_sizes, int n_in,
                              void* d_out, int out_size, void* d_ws, size_t ws_size,
                              hipStream_t stream) {
    const float* E = (const float*)d_in[0];
    const int* lab = (const int*)d_in[1];
    float* out = (float*)d_out;

    // Workspace layout:
    //   [0,8)        double accumulator
    //   [256, 16640) sq norms (4096 f32)
    //   [32768, +2MB) Ebf bf16 matrix (4096x256)
    double* accum = (double*)d_ws;
    float* sq = (float*)((char*)d_ws + 256);
    unsigned short* Ebf = (unsigned short*)((char*)d_ws + 32768);

    prep_kernel<<<BDIM, 256, 0, stream>>>(E, Ebf, sq, accum);
    dim3 grid(BDIM / 128, BDIM / 128);
    loss_mfma_kernel<<<grid, 256, 0, stream>>>(Ebf, lab, sq, accum);
    finalize_kernel<<<1, 1, 0, stream>>>(accum, out);
}

// Round 3
// 87.787 us; speedup vs baseline: 2.4017x; 1.0392x over previous
//
#include <hip/hip_runtime.h>

// Problem constants (from reference setup_inputs)
#define BDIM 4096
#define DDIM 256
#define NPAIRS 8386560.0   // B*(B-1)/2
#define NTB 32             // 4096 / 128 tiles per dim
#define NJOBS 528          // NTB*(NTB+1)/2 upper-triangular tile jobs

typedef __attribute__((ext_vector_type(8))) short bf16x8;  // MFMA A/B frag (4 VGPRs)
typedef __attribute__((ext_vector_type(4))) float f32x4;   // MFMA C/D frag

// ---------------------------------------------------------------------------
// Kernel 1: fp32 -> bf16 (RTN) + per-row squared norms. One wave per row,
// float4 loads (16 B/lane), uint2 packed bf16 stores (8 B/lane), no LDS.
// Grid: 1024 blocks x 256 threads (4 rows/block).
// ---------------------------------------------------------------------------
__global__ __launch_bounds__(256) void prep_kernel(const float* __restrict__ E,
                                                   unsigned short* __restrict__ Ebf,
                                                   float* __restrict__ sq,
                                                   double* __restrict__ accum) {
    int tid = threadIdx.x;
    int w = tid >> 6, lane = tid & 63;
    int row = blockIdx.x * 4 + w;

    float4 v = ((const float4*)(E + row * DDIM))[lane];

    float vv[4] = {v.x, v.y, v.z, v.w};
    unsigned int os[4];
    #pragma unroll
    for (int i = 0; i < 4; i++) {
        unsigned int u = __builtin_bit_cast(unsigned int, vv[i]);
        os[i] = (u + 0x7fffu + ((u >> 16) & 1u)) >> 16;   // RTN-even bf16
    }
    uint2 packed;
    packed.x = os[0] | (os[1] << 16);
    packed.y = os[2] | (os[3] << 16);
    ((uint2*)(Ebf + row * DDIM))[lane] = packed;

    float s = v.x * v.x + v.y * v.y + v.z * v.z + v.w * v.w;
    #pragma unroll
    for (int off = 32; off > 0; off >>= 1) s += __shfl_down(s, off, 64);
    if (lane == 0) sq[row] = s;
    if (row == 0 && lane == 0) *accum = 0.0;
}

// ---------------------------------------------------------------------------
// Kernel 2: 128x128 gram tile via bf16 MFMA + fused contrastive loss.
// Grid = 528 (only live upper-triangular jobs; flat-id triangular decode).
// BK=128: the whole K=256 in TWO staging phases (2 barriers/block vs 8).
// XOR-swizzled LDS chunk layout: global_load_lds forces dest = base+tid*16,
// so we permute the SOURCE chunk per thread (c = cs ^ (m&7)); fragment b128
// reads then spread uniformly over all 8 bank groups (2-way = free, m136),
// vs 8-way conflicts with the naive row-major layout.
// ---------------------------------------------------------------------------
__global__ __launch_bounds__(256) void loss_mfma_kernel(const unsigned short* __restrict__ Ebf,
                                                        const int* __restrict__ lab,
                                                        const float* __restrict__ sq,
                                                        double* __restrict__ accum) {
    // Triangular decode: row bi occupies flat ids [T(bi), T(bi+1)), T(b)=b*(65-b)/2
    int f = blockIdx.x;
    int bi = (int)((65.0 - sqrt(4225.0 - 8.0 * (double)f)) * 0.5);
    while ((bi + 1) * (65 - (bi + 1)) / 2 <= f) bi++;
    while (bi * (65 - bi) / 2 > f) bi--;
    int bj = bi + (f - bi * (65 - bi) / 2);

    __shared__ __align__(16) unsigned short As[128 * 128];   // 32 KB
    __shared__ __align__(16) unsigned short Bs[128 * 128];   // 32 KB

    int tid = threadIdx.x;
    int lane = tid & 63;
    int w = tid >> 6;
    int wr = w >> 1, wc = w & 1;              // wave's 64x64 quadrant
    int i0 = bi * 128, j0 = bj * 128;

    int frow = lane & 15;                      // fragment row index
    int q = lane >> 4;                         // quad
    int xq = frow & 7;                         // xor key for frag reads

    // Staging: LDS chunk idx = p*256 + tid holds global chunk (m = idx>>4,
    // c = (idx&15) ^ (m&7)). Since p*16 ≡ 0 mod 8, c is constant per thread.
    int srow = tid >> 4;                                   // 0..15
    int schunk = (tid & 15) ^ (srow & 7);                  // source 16B-chunk in k-slab
    const unsigned short* gA = Ebf + (i0 + srow) * DDIM + schunk * 8;
    const unsigned short* gB = Ebf + (j0 + srow) * DDIM + schunk * 8;
    unsigned short* lA = As + tid * 8;                     // byte offset tid*16
    unsigned short* lB = Bs + tid * 8;

    f32x4 acc[4][4] = {};

    #pragma unroll
    for (int half = 0; half < 2; half++) {
        int k0 = half * 128;   // halfword offset of this k-slab
        #pragma unroll
        for (int p = 0; p < 8; p++)
            __builtin_amdgcn_global_load_lds(
                (const __attribute__((address_space(1))) void*)(gA + p * 16 * DDIM + k0),
                (__attribute__((address_space(3))) void*)(lA + p * 2048), 16, 0, 0);
        #pragma unroll
        for (int p = 0; p < 8; p++)
            __builtin_amdgcn_global_load_lds(
                (const __attribute__((address_space(1))) void*)(gB + p * 16 * DDIM + k0),
                (__attribute__((address_space(3))) void*)(lB + p * 2048), 16, 0, 0);
        __syncthreads();

        #pragma unroll
        for (int s = 0; s < 4; s++) {
            int cw = s * 4 + q;                // wanted chunk = k-halfwords [cw*8, cw*8+8)
            bf16x8 af[4], bfr[4];
            #pragma unroll
            for (int r = 0; r < 4; r++) {
                int row = wr * 64 + r * 16 + frow;
                af[r] = *(const bf16x8*)(As + (row * 16 + (cw ^ xq)) * 8);
            }
            #pragma unroll
            for (int c = 0; c < 4; c++) {
                int row = wc * 64 + c * 16 + frow;
                bfr[c] = *(const bf16x8*)(Bs + (row * 16 + (cw ^ xq)) * 8);
            }
            #pragma unroll
            for (int r = 0; r < 4; r++)
                #pragma unroll
                for (int c = 0; c < 4; c++)
                    acc[r][c] = __builtin_amdgcn_mfma_f32_16x16x32_bf16(af[r], bfr[c], acc[r][c], 0, 0, 0);
        }
        if (half == 0) __syncthreads();
    }

    // Epilogue: C/D layout col = lane&15, row = (lane>>4)*4 + reg (verified R2).
    int rowbase = i0 + wr * 64 + q * 4;
    int colbase = j0 + wc * 64 + frow;

    float sqi[16];
    int li[16];
    #pragma unroll
    for (int r = 0; r < 4; r++)
        #pragma unroll
        for (int reg = 0; reg < 4; reg++) {
            int gi = rowbase + r * 16 + reg;
            sqi[r * 4 + reg] = sq[gi];
            li[r * 4 + reg] = lab[gi];
        }

    float lsum = 0.f;
    #pragma unroll
    for (int c = 0; c < 4; c++) {
        int gj = colbase + c * 16;
        float sqj = sq[gj];
        int lj = lab[gj];
        #pragma unroll
        for (int r = 0; r < 4; r++) {
            #pragma unroll
            for (int reg = 0; reg < 4; reg++) {
                int gi = rowbase + r * 16 + reg;
                if (gj > gi) {
                    float d2 = sqi[r * 4 + reg] + sqj - 2.f * acc[r][c][reg];
                    d2 = fmaxf(d2, 0.f) + 1e-8f;
                    float loss;
                    if (li[r * 4 + reg] == lj) {
                        loss = 0.5f * d2;
                    } else {
                        float dist = sqrtf(d2);
                        float m1 = fmaxf(1.0f - dist, 0.f);
                        loss = 0.5f * m1 * m1;
                    }
                    lsum += loss;
                }
            }
        }
    }

    // Block reduction: wave shuffle -> LDS across 4 waves -> one atomic per block.
    #pragma unroll
    for (int off = 32; off > 0; off >>= 1) lsum += __shfl_down(lsum, off, 64);
    __shared__ float wsum[4];
    if (lane == 0) wsum[w] = lsum;
    __syncthreads();
    if (tid == 0) {
        double bs = (double)wsum[0] + (double)wsum[1] + (double)wsum[2] + (double)wsum[3];
        atomicAdd(accum, bs);
    }
}

// ---------------------------------------------------------------------------
// Kernel 3: final division, write scalar output
// ---------------------------------------------------------------------------
__global__ void finalize_kernel(const double* __restrict__ accum, float* __restrict__ out) {
    out[0] = (float)(*accum / (NPAIRS + 1e-8));
}

extern "C" void kernel_launch(void* const* d_in, const int* in_sizes, int n_in,
                              void* d_out, int out_size, void* d_ws, size_t ws_size,
                              hipStream_t stream) {
    const float* E = (const float*)d_in[0];
    const int* lab = (const int*)d_in[1];
    float* out = (float*)d_out;

    // Workspace layout:
    //   [0,8)         double accumulator
    //   [256, 16640)  sq norms (4096 f32)
    //   [32768, +2MB) Ebf bf16 matrix (4096x256)
    double* accum = (double*)d_ws;
    float* sq = (float*)((char*)d_ws + 256);
    unsigned short* Ebf = (unsigned short*)((char*)d_ws + 32768);

    prep_kernel<<<BDIM / 4, 256, 0, stream>>>(E, Ebf, sq, accum);
    loss_mfma_kernel<<<NJOBS, 256, 0, stream>>>(Ebf, lab, sq, accum);
    finalize_kernel<<<1, 1, 0, stream>>>(accum, out);
}

// Round 4
// 83.372 us; speedup vs baseline: 2.5289x; 1.0530x over previous
//
#include <hip/hip_runtime.h>

// Problem constants (from reference setup_inputs)
#define BDIM 4096
#define DDIM 256
#define NPAIRS 8386560.0   // B*(B-1)/2
#define NTB 32             // 4096 / 128 tiles per dim
#define NJOBS 528          // NTB*(NTB+1)/2 upper-triangular tile jobs

typedef __attribute__((ext_vector_type(8))) short bf16x8;  // MFMA A/B frag (4 VGPRs)
typedef __attribute__((ext_vector_type(4))) float f32x4;   // MFMA C/D frag

// ---------------------------------------------------------------------------
// Kernel 1: fp32 -> bf16 (RTN) + per-row squared norms. One wave per row,
// float4 loads (16 B/lane), uint2 packed bf16 stores (8 B/lane), no LDS.
// Grid: 1024 blocks x 256 threads (4 rows/block).
// ---------------------------------------------------------------------------
__global__ __launch_bounds__(256) void prep_kernel(const float* __restrict__ E,
                                                   unsigned short* __restrict__ Ebf,
                                                   float* __restrict__ sq) {
    int tid = threadIdx.x;
    int w = tid >> 6, lane = tid & 63;
    int row = blockIdx.x * 4 + w;

    float4 v = ((const float4*)(E + row * DDIM))[lane];

    float vv[4] = {v.x, v.y, v.z, v.w};
    unsigned int os[4];
    #pragma unroll
    for (int i = 0; i < 4; i++) {
        unsigned int u = __builtin_bit_cast(unsigned int, vv[i]);
        os[i] = (u + 0x7fffu + ((u >> 16) & 1u)) >> 16;   // RTN-even bf16
    }
    uint2 packed;
    packed.x = os[0] | (os[1] << 16);
    packed.y = os[2] | (os[3] << 16);
    ((uint2*)(Ebf + row * DDIM))[lane] = packed;

    float s = v.x * v.x + v.y * v.y + v.z * v.z + v.w * v.w;
    #pragma unroll
    for (int off = 32; off > 0; off >>= 1) s += __shfl_down(s, off, 64);
    if (lane == 0) sq[row] = s;
}

// ---------------------------------------------------------------------------
// Kernel 2: 128x128 gram tile via bf16 MFMA + fused contrastive loss.
// Grid = 528 (only live upper-triangular jobs; flat-id triangular decode).
// BK=128: the whole K=256 in TWO staging phases. XOR-swizzled LDS chunk
// layout (see R3 notes): staging permutes the SOURCE chunk per thread so
// fragment b128 reads spread across all bank groups (2-way = free, m136).
// NO atomics: each block writes its partial sum to a distinct slot —
// R4 change, removing the 528-way same-address f64 atomic serialization.
// ---------------------------------------------------------------------------
__global__ __launch_bounds__(256) void loss_mfma_kernel(const unsigned short* __restrict__ Ebf,
                                                        const int* __restrict__ lab,
                                                        const float* __restrict__ sq,
                                                        double* __restrict__ partial) {
    // Triangular decode: row bi occupies flat ids [T(bi), T(bi+1)), T(b)=b*(65-b)/2
    int f = blockIdx.x;
    int bi = (int)((65.0 - sqrt(4225.0 - 8.0 * (double)f)) * 0.5);
    while ((bi + 1) * (65 - (bi + 1)) / 2 <= f) bi++;
    while (bi * (65 - bi) / 2 > f) bi--;
    int bj = bi + (f - bi * (65 - bi) / 2);

    __shared__ __align__(16) unsigned short As[128 * 128];   // 32 KB
    __shared__ __align__(16) unsigned short Bs[128 * 128];   // 32 KB

    int tid = threadIdx.x;
    int lane = tid & 63;
    int w = tid >> 6;
    int wr = w >> 1, wc = w & 1;              // wave's 64x64 quadrant
    int i0 = bi * 128, j0 = bj * 128;

    int frow = lane & 15;                      // fragment row index
    int q = lane >> 4;                         // quad
    int xq = frow & 7;                         // xor key for frag reads

    // Staging: LDS chunk idx = p*256 + tid holds global chunk (m = idx>>4,
    // c = (idx&15) ^ (m&7)). Since p*16 ≡ 0 mod 8, c is constant per thread.
    int srow = tid >> 4;                                   // 0..15
    int schunk = (tid & 15) ^ (srow & 7);                  // source 16B-chunk in k-slab
    const unsigned short* gA = Ebf + (i0 + srow) * DDIM + schunk * 8;
    const unsigned short* gB = Ebf + (j0 + srow) * DDIM + schunk * 8;
    unsigned short* lA = As + tid * 8;                     // byte offset tid*16
    unsigned short* lB = Bs + tid * 8;

    f32x4 acc[4][4] = {};

    #pragma unroll
    for (int half = 0; half < 2; half++) {
        int k0 = half * 128;   // halfword offset of this k-slab
        #pragma unroll
        for (int p = 0; p < 8; p++)
            __builtin_amdgcn_global_load_lds(
                (const __attribute__((address_space(1))) void*)(gA + p * 16 * DDIM + k0),
                (__attribute__((address_space(3))) void*)(lA + p * 2048), 16, 0, 0);
        #pragma unroll
        for (int p = 0; p < 8; p++)
            __builtin_amdgcn_global_load_lds(
                (const __attribute__((address_space(1))) void*)(gB + p * 16 * DDIM + k0),
                (__attribute__((address_space(3))) void*)(lB + p * 2048), 16, 0, 0);
        __syncthreads();

        #pragma unroll
        for (int s = 0; s < 4; s++) {
            int cw = s * 4 + q;                // wanted chunk = k-halfwords [cw*8, cw*8+8)
            bf16x8 af[4], bfr[4];
            #pragma unroll
            for (int r = 0; r < 4; r++) {
                int row = wr * 64 + r * 16 + frow;
                af[r] = *(const bf16x8*)(As + (row * 16 + (cw ^ xq)) * 8);
            }
            #pragma unroll
            for (int c = 0; c < 4; c++) {
                int row = wc * 64 + c * 16 + frow;
                bfr[c] = *(const bf16x8*)(Bs + (row * 16 + (cw ^ xq)) * 8);
            }
            #pragma unroll
            for (int r = 0; r < 4; r++)
                #pragma unroll
                for (int c = 0; c < 4; c++)
                    acc[r][c] = __builtin_amdgcn_mfma_f32_16x16x32_bf16(af[r], bfr[c], acc[r][c], 0, 0, 0);
        }
        if (half == 0) __syncthreads();
    }

    // Epilogue: C/D layout col = lane&15, row = (lane>>4)*4 + reg (verified R2).
    int rowbase = i0 + wr * 64 + q * 4;
    int colbase = j0 + wc * 64 + frow;

    float sqi[16];
    int li[16];
    #pragma unroll
    for (int r = 0; r < 4; r++)
        #pragma unroll
        for (int reg = 0; reg < 4; reg++) {
            int gi = rowbase + r * 16 + reg;
            sqi[r * 4 + reg] = sq[gi];
            li[r * 4 + reg] = lab[gi];
        }

    float lsum = 0.f;
    #pragma unroll
    for (int c = 0; c < 4; c++) {
        int gj = colbase + c * 16;
        float sqj = sq[gj];
        int lj = lab[gj];
        #pragma unroll
        for (int r = 0; r < 4; r++) {
            #pragma unroll
            for (int reg = 0; reg < 4; reg++) {
                int gi = rowbase + r * 16 + reg;
                if (gj > gi) {
                    float d2 = sqi[r * 4 + reg] + sqj - 2.f * acc[r][c][reg];
                    d2 = fmaxf(d2, 0.f) + 1e-8f;
                    float loss;
                    if (li[r * 4 + reg] == lj) {
                        loss = 0.5f * d2;
                    } else {
                        float dist = sqrtf(d2);
                        float m1 = fmaxf(1.0f - dist, 0.f);
                        loss = 0.5f * m1 * m1;
                    }
                    lsum += loss;
                }
            }
        }
    }

    // Block reduction: wave shuffle -> LDS across 4 waves -> ONE plain store
    // per block to a distinct slot (no atomics).
    #pragma unroll
    for (int off = 32; off > 0; off >>= 1) lsum += __shfl_down(lsum, off, 64);
    __shared__ float wsum[4];
    if (lane == 0) wsum[w] = lsum;
    __syncthreads();
    if (tid == 0) {
        double bs = (double)wsum[0] + (double)wsum[1] + (double)wsum[2] + (double)wsum[3];
        partial[f] = bs;
    }
}

// ---------------------------------------------------------------------------
// Kernel 3: reduce 528 per-block partials, divide, write scalar output.
// ---------------------------------------------------------------------------
__global__ __launch_bounds__(256) void finalize_kernel(const double* __restrict__ partial,
                                                       float* __restrict__ out) {
    int tid = threadIdx.x;
    double s = 0.0;
    for (int i = tid; i < NJOBS; i += 256) s += partial[i];
    #pragma unroll
    for (int off = 32; off > 0; off >>= 1) s += __shfl_down(s, off, 64);
    __shared__ double ws[4];
    int w = tid >> 6, lane = tid & 63;
    if (lane == 0) ws[w] = s;
    __syncthreads();
    if (tid == 0) out[0] = (float)((ws[0] + ws[1] + ws[2] + ws[3]) / (NPAIRS + 1e-8));
}

extern "C" void kernel_launch(void* const* d_in, const int* in_sizes, int n_in,
                              void* d_out, int out_size, void* d_ws, size_t ws_size,
                              hipStream_t stream) {
    const float* E = (const float*)d_in[0];
    const int* lab = (const int*)d_in[1];
    float* out = (float*)d_out;

    // Workspace layout:
    //   [0, 4224)     528 per-block partial doubles (all written every launch)
    //   [8192, 24576) sq norms (4096 f32)
    //   [32768, +2MB) Ebf bf16 matrix (4096x256)
    double* partial = (double*)d_ws;
    float* sq = (float*)((char*)d_ws + 8192);
    unsigned short* Ebf = (unsigned short*)((char*)d_ws + 32768);

    prep_kernel<<<BDIM / 4, 256, 0, stream>>>(E, Ebf, sq);
    loss_mfma_kernel<<<NJOBS, 256, 0, stream>>>(Ebf, lab, sq, partial);
    finalize_kernel<<<1, 256, 0, stream>>>(partial, out);
}

// Round 5
// 79.035 us; speedup vs baseline: 2.6677x; 1.0549x over previous
//
#include <hip/hip_runtime.h>

// Problem constants (from reference setup_inputs)
#define BDIM 4096
#define DDIM 256
#define NPAIRS 8386560.0   // B*(B-1)/2
#define NTB 32             // 4096 / 128 tiles per dim
#define NJOBS 528          // NTB*(NTB+1)/2 upper-triangular tile jobs

typedef __attribute__((ext_vector_type(8))) short bf16x8;  // MFMA A/B frag (4 VGPRs)
typedef __attribute__((ext_vector_type(4))) float f32x4;   // MFMA C/D frag

// ---------------------------------------------------------------------------
// Kernel 1: fp32 -> bf16 (RTN) + per-row squared norms. One wave per row,
// float4 loads, uint2 packed bf16 stores, no LDS.
// ---------------------------------------------------------------------------
__global__ __launch_bounds__(256) void prep_kernel(const float* __restrict__ E,
                                                   unsigned short* __restrict__ Ebf,
                                                   float* __restrict__ sq) {
    int tid = threadIdx.x;
    int w = tid >> 6, lane = tid & 63;
    int row = blockIdx.x * 4 + w;

    float4 v = ((const float4*)(E + row * DDIM))[lane];

    float vv[4] = {v.x, v.y, v.z, v.w};
    unsigned int os[4];
    #pragma unroll
    for (int i = 0; i < 4; i++) {
        unsigned int u = __builtin_bit_cast(unsigned int, vv[i]);
        os[i] = (u + 0x7fffu + ((u >> 16) & 1u)) >> 16;   // RTN-even bf16
    }
    uint2 packed;
    packed.x = os[0] | (os[1] << 16);
    packed.y = os[2] | (os[3] << 16);
    ((uint2*)(Ebf + row * DDIM))[lane] = packed;

    float s = v.x * v.x + v.y * v.y + v.z * v.z + v.w * v.w;
    #pragma unroll
    for (int off = 32; off > 0; off >>= 1) s += __shfl_down(s, off, 64);
    if (lane == 0) sq[row] = s;
}

// ---------------------------------------------------------------------------
// Kernel 2: 128x128 gram tile via bf16 MFMA + fused contrastive loss.
// R5 changes (concurrency attack):
//  - BK=64 single-buffered: LDS 32 KB -> 4 blocks/CU (launch_bounds(256,4)),
//    4 short staging phases instead of 2 monster vmcnt(0) drains.
//  - XCD-grouped job map g=(f%8)*66+f/8: round-robin block->XCD then gives
//    each XCD a contiguous triangular chunk (same-bi A-tile L2 reuse).
//  - Diagonal blocks skip B staging (frags read from As).
// XOR-swizzled LDS chunk layout (8 chunks/row of 16B): slot (m, c') holds
// global chunk c'^(m&7), so frag b128 reads spread over bank groups (2-way =
// free, m136) while global_load_lds staging stays dest = base + tid*16.
// ---------------------------------------------------------------------------
__global__ __launch_bounds__(256, 4) void loss_mfma_kernel(const unsigned short* __restrict__ Ebf,
                                                           const int* __restrict__ lab,
                                                           const float* __restrict__ sq,
                                                           double* __restrict__ partial) {
    int f = blockIdx.x;
    int g = (f & 7) * 66 + (f >> 3);   // XCD-contiguous triangular chunking
    // Triangular decode: row bi occupies ids [T(bi), T(bi+1)), T(b)=b*(65-b)/2
    int bi = (int)((65.0 - sqrt(4225.0 - 8.0 * (double)g)) * 0.5);
    while ((bi + 1) * (65 - (bi + 1)) / 2 <= g) bi++;
    while (bi * (65 - bi) / 2 > g) bi--;
    int bj = bi + (g - bi * (65 - bi) / 2);

    __shared__ __align__(16) unsigned short As[128 * 64];   // 16 KB
    __shared__ __align__(16) unsigned short Bs[128 * 64];   // 16 KB

    int tid = threadIdx.x;
    int lane = tid & 63;
    int w = tid >> 6;
    int wr = w >> 1, wc = w & 1;              // wave's 64x64 quadrant
    int i0 = bi * 128, j0 = bj * 128;
    bool diag = (bi == bj);

    int frow = lane & 15;                      // fragment row index
    int q = lane >> 4;                         // quad: k-offset q*8

    // Staging: LDS slot idx = p*256 + tid -> m = p*32 + (tid>>3), c' = tid&7;
    // slot holds global chunk c' ^ (m&7) = (tid&7) ^ ((tid>>3)&7).
    int srl = tid >> 3;                                    // 0..31
    int sch = (tid & 7) ^ (srl & 7);                       // source 16B chunk
    const unsigned short* gA = Ebf + (i0 + srl) * DDIM + sch * 8;
    const unsigned short* gB = Ebf + (j0 + srl) * DDIM + sch * 8;
    unsigned short* lA = As + tid * 8;                     // byte offset tid*16
    unsigned short* lB = Bs + tid * 8;

    f32x4 acc[4][4] = {};

    for (int ph = 0; ph < 4; ph++) {
        int k0 = ph * 64;   // halfword offset of this k-slab
        #pragma unroll
        for (int p = 0; p < 4; p++)
            __builtin_amdgcn_global_load_lds(
                (const __attribute__((address_space(1))) void*)(gA + p * 32 * DDIM + k0),
                (__attribute__((address_space(3))) void*)(lA + p * 2048), 16, 0, 0);
        if (!diag) {
            #pragma unroll
            for (int p = 0; p < 4; p++)
                __builtin_amdgcn_global_load_lds(
                    (const __attribute__((address_space(1))) void*)(gB + p * 32 * DDIM + k0),
                    (__attribute__((address_space(3))) void*)(lB + p * 2048), 16, 0, 0);
        }
        __syncthreads();

        const unsigned short* Bbase = diag ? As : Bs;
        #pragma unroll
        for (int s = 0; s < 2; s++) {
            int cw = s * 4 + q;                // wanted chunk within 8-chunk row
            bf16x8 af[4], bfr[4];
            #pragma unroll
            for (int r = 0; r < 4; r++) {
                int row = wr * 64 + r * 16 + frow;
                af[r] = *(const bf16x8*)(As + (row * 8 + (cw ^ (row & 7))) * 8);
            }
            #pragma unroll
            for (int c = 0; c < 4; c++) {
                int row = wc * 64 + c * 16 + frow;
                bfr[c] = *(const bf16x8*)(Bbase + (row * 8 + (cw ^ (row & 7))) * 8);
            }
            #pragma unroll
            for (int r = 0; r < 4; r++)
                #pragma unroll
                for (int c = 0; c < 4; c++)
                    acc[r][c] = __builtin_amdgcn_mfma_f32_16x16x32_bf16(af[r], bfr[c], acc[r][c], 0, 0, 0);
        }
        if (ph < 3) __syncthreads();
    }

    // Epilogue: C/D layout col = lane&15, row = (lane>>4)*4 + reg.
    int rowbase = i0 + wr * 64 + q * 4;
    int colbase = j0 + wc * 64 + frow;

    float sqi[16];
    int li[16];
    #pragma unroll
    for (int r = 0; r < 4; r++)
        #pragma unroll
        for (int reg = 0; reg < 4; reg++) {
            int gi = rowbase + r * 16 + reg;
            sqi[r * 4 + reg] = sq[gi];
            li[r * 4 + reg] = lab[gi];
        }

    float lsum = 0.f;
    #pragma unroll
    for (int c = 0; c < 4; c++) {
        int gj = colbase + c * 16;
        float sqj = sq[gj];
        int lj = lab[gj];
        #pragma unroll
        for (int r = 0; r < 4; r++) {
            #pragma unroll
            for (int reg = 0; reg < 4; reg++) {
                int gi = rowbase + r * 16 + reg;
                if (gj > gi) {
                    float d2 = sqi[r * 4 + reg] + sqj - 2.f * acc[r][c][reg];
                    d2 = fmaxf(d2, 0.f) + 1e-8f;
                    float loss;
                    if (li[r * 4 + reg] == lj) {
                        loss = 0.5f * d2;
                    } else {
                        float dist = sqrtf(d2);
                        float m1 = fmaxf(1.0f - dist, 0.f);
                        loss = 0.5f * m1 * m1;
                    }
                    lsum += loss;
                }
            }
        }
    }

    // Block reduction: wave shuffle -> LDS -> ONE plain store per block.
    #pragma unroll
    for (int off = 32; off > 0; off >>= 1) lsum += __shfl_down(lsum, off, 64);
    __shared__ float wsum[4];
    if (lane == 0) wsum[w] = lsum;
    __syncthreads();
    if (tid == 0) {
        double bs = (double)wsum[0] + (double)wsum[1] + (double)wsum[2] + (double)wsum[3];
        partial[f] = bs;
    }
}

// ---------------------------------------------------------------------------
// Kernel 3: reduce 528 per-block partials, divide, write scalar output.
// ---------------------------------------------------------------------------
__global__ __launch_bounds__(256) void finalize_kernel(const double* __restrict__ partial,
                                                       float* __restrict__ out) {
    int tid = threadIdx.x;
    double s = 0.0;
    for (int i = tid; i < NJOBS; i += 256) s += partial[i];
    #pragma unroll
    for (int off = 32; off > 0; off >>= 1) s += __shfl_down(s, off, 64);
    __shared__ double ws[4];
    int w = tid >> 6, lane = tid & 63;
    if (lane == 0) ws[w] = s;
    __syncthreads();
    if (tid == 0) out[0] = (float)((ws[0] + ws[1] + ws[2] + ws[3]) / (NPAIRS + 1e-8));
}

extern "C" void kernel_launch(void* const* d_in, const int* in_sizes, int n_in,
                              void* d_out, int out_size, void* d_ws, size_t ws_size,
                              hipStream_t stream) {
    const float* E = (const float*)d_in[0];
    const int* lab = (const int*)d_in[1];
    float* out = (float*)d_out;

    // Workspace layout:
    //   [0, 4224)     528 per-block partial doubles (all written every launch)
    //   [8192, 24576) sq norms (4096 f32)
    //   [32768, +2MB) Ebf bf16 matrix (4096x256)
    double* partial = (double*)d_ws;
    float* sq = (float*)((char*)d_ws + 8192);
    unsigned short* Ebf = (unsigned short*)((char*)d_ws + 32768);

    prep_kernel<<<BDIM / 4, 256, 0, stream>>>(E, Ebf, sq);
    loss_mfma_kernel<<<NJOBS, 256, 0, stream>>>(Ebf, lab, sq, partial);
    finalize_kernel<<<1, 256, 0, stream>>>(partial, out);
}